// Round 3
// baseline (324.617 us; speedup 1.0000x reference)
//
#include <hip/hip_runtime.h>

#define NN 4096
#define BB 32
#define UU 64
#define MAXNNZ 96

typedef float f32x4 __attribute__((ext_vector_type(4)));
typedef float f32x2 __attribute__((ext_vector_type(2)));
typedef short bf16x8 __attribute__((ext_vector_type(8)));
typedef unsigned short us8 __attribute__((ext_vector_type(8)));
typedef unsigned short us4 __attribute__((ext_vector_type(4)));

__device__ __forceinline__ float bf2f(unsigned short u) {
    return __uint_as_float(((unsigned)u) << 16);
}
__device__ __forceinline__ unsigned short f2bf(float f) {
    unsigned x = __float_as_uint(f);
    x += 0x7fffu + ((x >> 16) & 1u);
    return (unsigned short)(x >> 16);
}

// ---------------------------------------------------------------------------
// K1: dense support (4096x4096 f32) -> padded ELL (cols int32, vals f32, cnt)
// ---------------------------------------------------------------------------
__global__ void build_ell(const float* __restrict__ sup, int* __restrict__ cols,
                          float* __restrict__ vals, int* __restrict__ cnt) {
    int row  = blockIdx.x * 4 + (threadIdx.x >> 6);
    int lane = threadIdx.x & 63;
    const float* rp = sup + (size_t)row * NN;
    int base = 0;
    for (int ch = 0; ch < NN / 64; ++ch) {
        float v = rp[ch * 64 + lane];
        unsigned long long m = __ballot(v != 0.0f);
        int pos = __popcll(m & ((1ull << lane) - 1ull));
        if (v != 0.0f) {
            int idx = base + pos;
            if (idx < MAXNNZ) {
                cols[row * MAXNNZ + idx] = ch * 64 + lane;
                vals[row * MAXNNZ + idx] = v;
            }
        }
        base += __popcll(m);
    }
    if (lane == 0) cnt[row] = base < MAXNNZ ? base : MAXNNZ;
}

// ---------------------------------------------------------------------------
// K2: build Xall (N x 4096) bf16: cols [0,2048) = inputs, [2048,4096) = hx
// ---------------------------------------------------------------------------
__global__ void build_x0(const float* __restrict__ inp, const float* __restrict__ hxp,
                         unsigned short* __restrict__ Xall) {
    size_t tt = (size_t)blockIdx.x * 256 + threadIdx.x;
    size_t e  = tt * 4;
    int half  = e >= (size_t)8388608;
    size_t id = e & 8388607ull;               // b*262144 + n*64 + d
    const float* src = half ? hxp : inp;
    float4 f = *(const float4*)(src + id);
    int d = (int)(id & 63);
    int n = (int)((id >> 6) & 4095);
    int b = (int)(id >> 18);
    us4 o;
    o[0] = f2bf(f.x); o[1] = f2bf(f.y); o[2] = f2bf(f.z); o[3] = f2bf(f.w);
    *(us4*)(Xall + (size_t)n * 4096 + (size_t)half * 2048 + b * 64 + d) = o;
}

// ---------------------------------------------------------------------------
// K3: permute + transpose + bf16-cast weights.
// f = m*128 + s  (m in 0..2, s in 0..127), original row s*3+m.
// ---------------------------------------------------------------------------
__global__ void prep_w(const float* __restrict__ Wru, const float* __restrict__ Wc,
                       unsigned short* __restrict__ Wt1, unsigned short* __restrict__ Wt2) {
    int t = blockIdx.x * 256 + threadIdx.x;   // grid 288*256 = 73728 exactly
    if (t < 49152) {
        int o = t / 384, f = t - o * 384;
        int s = f & 127, m = f >> 7;
        Wt1[t] = f2bf(Wru[(s * 3 + m) * 128 + o]);
    } else {
        int u = t - 49152;
        int o = u / 384, f = u - o * 384;
        int s = f & 127, m = f >> 7;
        Wt2[u] = f2bf(Wc[(s * 3 + m) * 64 + o]);
    }
}

// ---------------------------------------------------------------------------
// SpMM: Y[row, c] = sum_k vals[row,k] * X[cols[row,k], c]
// CHEB: Y = 2*(L@X) - Z0
// One wave per (row, 512-col chunk); 8 cols/lane (16B gathers), 8 in flight.
// ---------------------------------------------------------------------------
template <bool CHEB>
__launch_bounds__(256)
__global__ void spmm_kernel(const int* __restrict__ cols, const float* __restrict__ vals,
                            const int* __restrict__ cnt, const unsigned short* __restrict__ X,
                            const unsigned short* __restrict__ Z0,
                            unsigned short* __restrict__ Y, int ncols) {
    int T = gridDim.x;
    int fid = blockIdx.x;
    int v = (fid & 7) * (T >> 3) + (fid >> 3);   // XCD k owns v in [k*T/8,(k+1)*T/8)
    int chunk = v >> 10;                          // 1024 row-groups per chunk
    int rg = v & 1023;
    int row = __builtin_amdgcn_readfirstlane(rg * 4 + (threadIdx.x >> 6));
    int lane = threadIdx.x & 63;
    int c = chunk * 512 + lane * 8;
    const int* cp = cols + row * MAXNNZ;
    const float* vp = vals + row * MAXNNZ;
    int kc = cnt[row];
    f32x2 acc0 = {0.f, 0.f}, acc1 = {0.f, 0.f}, acc2 = {0.f, 0.f}, acc3 = {0.f, 0.f};
    int k = 0;
    for (; k + 8 <= kc; k += 8) {
        us8 xx[8];
        float ss[8];
#pragma unroll
        for (int u = 0; u < 8; ++u) {
            xx[u] = *(const us8*)(X + (size_t)cp[k + u] * ncols + c);
            ss[u] = vp[k + u];
        }
#pragma unroll
        for (int u = 0; u < 8; ++u) {
            f32x2 w = {ss[u], ss[u]};
            const unsigned* p = (const unsigned*)&xx[u];
            f32x2 xv;
            xv.x = __uint_as_float(p[0] << 16); xv.y = __uint_as_float(p[0] & 0xffff0000u);
            acc0 = __builtin_elementwise_fma(w, xv, acc0);
            xv.x = __uint_as_float(p[1] << 16); xv.y = __uint_as_float(p[1] & 0xffff0000u);
            acc1 = __builtin_elementwise_fma(w, xv, acc1);
            xv.x = __uint_as_float(p[2] << 16); xv.y = __uint_as_float(p[2] & 0xffff0000u);
            acc2 = __builtin_elementwise_fma(w, xv, acc2);
            xv.x = __uint_as_float(p[3] << 16); xv.y = __uint_as_float(p[3] & 0xffff0000u);
            acc3 = __builtin_elementwise_fma(w, xv, acc3);
        }
    }
    for (; k < kc; ++k) {
        int j = cp[k];
        float s = vp[k];
        f32x2 w = {s, s};
        us8 x = *(const us8*)(X + (size_t)j * ncols + c);
        const unsigned* p = (const unsigned*)&x;
        f32x2 xv;
        xv.x = __uint_as_float(p[0] << 16); xv.y = __uint_as_float(p[0] & 0xffff0000u);
        acc0 = __builtin_elementwise_fma(w, xv, acc0);
        xv.x = __uint_as_float(p[1] << 16); xv.y = __uint_as_float(p[1] & 0xffff0000u);
        acc1 = __builtin_elementwise_fma(w, xv, acc1);
        xv.x = __uint_as_float(p[2] << 16); xv.y = __uint_as_float(p[2] & 0xffff0000u);
        acc2 = __builtin_elementwise_fma(w, xv, acc2);
        xv.x = __uint_as_float(p[3] << 16); xv.y = __uint_as_float(p[3] & 0xffff0000u);
        acc3 = __builtin_elementwise_fma(w, xv, acc3);
    }
    float a[8] = {acc0.x, acc0.y, acc1.x, acc1.y, acc2.x, acc2.y, acc3.x, acc3.y};
    if (CHEB) {
        us8 z = __builtin_nontemporal_load((const us8*)(Z0 + (size_t)row * ncols + c));
        const unsigned* pz = (const unsigned*)&z;
#pragma unroll
        for (int i = 0; i < 4; ++i) {
            a[2 * i]     = 2.f * a[2 * i]     - __uint_as_float(pz[i] << 16);
            a[2 * i + 1] = 2.f * a[2 * i + 1] - __uint_as_float(pz[i] & 0xffff0000u);
        }
    }
    us8 o;
#pragma unroll
    for (int i = 0; i < 8; ++i) o[i] = f2bf(a[i]);
    __builtin_nontemporal_store(o, (us8*)(Y + (size_t)row * ncols + c));
}

// ---------------------------------------------------------------------------
// Feature GEMM, n-blocked: block = 4 graph nodes x all 32 batches = 128 rows.
// GEMM row r = dn*32 + b  (dn = n - n0). Each K-step's A-tile is 4 x 4KB
// CONTIGUOUS runs (one per node row) -> pure streaming reads.
// Sources ordered by K-step: s0..s5 = in_m0, st_m0, in_m1, st_m1, in_m2, st_m2
// (features f = m*128 + half*64 + d, matching prep_w's layout).
// Register-prefetch pipeline: load step k+1 while MFMAing step k.
// GATE epilogue: sigmoid -> r*h (bf16, X2st) and u (bf16, ubuf).
// FINAL epilogue: tanh -> out = u*h + (1-u)*c.
// ---------------------------------------------------------------------------
template <bool GATE>
__launch_bounds__(256)
__global__ void gemm_kernel(
    const unsigned short* __restrict__ s0, const unsigned short* __restrict__ s1,
    const unsigned short* __restrict__ s2, const unsigned short* __restrict__ s3,
    const unsigned short* __restrict__ s4, const unsigned short* __restrict__ s5,
    int strideSt,
    const unsigned short* __restrict__ Wt, const float* __restrict__ bias,
    const float* __restrict__ hx, unsigned short* __restrict__ ubuf,
    unsigned short* __restrict__ x2st, float* __restrict__ outp) {
    constexpr int OC = GATE ? 128 : 64;
    constexpr int MF = GATE ? 8 : 4;
    __shared__ __align__(16) unsigned short A_lds[128 * 72];  // 144B row stride
    __shared__ __align__(16) unsigned short W_lds[OC * 72];
    const int t = threadIdx.x;
    const int w = t >> 6, l = t & 63;
    const int n0 = blockIdx.x * 4;
    const int dn = w;              // staging: wave w streams node row n0+w
    const int q = l;               // 32-element chunk index within the 2048-col row
    const int o = t >> 1;          // W staging row (output channel)
    const int wq = t & 1;
    const int rowBaseW = GATE ? 0 : ((w >> 1) * 64);
    const int colBaseW = GATE ? (w * 32) : ((w & 1) * 32);
    f32x4 acc[MF][2];
#pragma unroll
    for (int i = 0; i < MF; ++i)
#pragma unroll
        for (int j = 0; j < 2; ++j)
#pragma unroll
            for (int r2 = 0; r2 < 4; ++r2) acc[i][j][r2] = 0.f;

    us8 avC[4], wvC[4], avN[4], wvN[4];
    {
        const unsigned short* a = s0 + (size_t)(n0 + dn) * NN + q * 32;
        avC[0] = *(const us8*)(a);      avC[1] = *(const us8*)(a + 8);
        avC[2] = *(const us8*)(a + 16); avC[3] = *(const us8*)(a + 24);
        if (o < OC) {
            const unsigned short* ww = Wt + o * 384 + wq * 32;
            wvC[0] = *(const us8*)(ww);      wvC[1] = *(const us8*)(ww + 8);
            wvC[2] = *(const us8*)(ww + 16); wvC[3] = *(const us8*)(ww + 24);
        }
    }

#pragma unroll
    for (int kk2 = 0; kk2 < 6; ++kk2) {
        __syncthreads();
        {   // commit staged tile to LDS
            unsigned short* d = &A_lds[(dn * 32 + (q >> 1)) * 72 + (q & 1) * 32];
            *(us8*)(d) = avC[0]; *(us8*)(d + 8) = avC[1];
            *(us8*)(d + 16) = avC[2]; *(us8*)(d + 24) = avC[3];
            if (o < OC) {
                unsigned short* dw = &W_lds[o * 72 + wq * 32];
                *(us8*)(dw) = wvC[0]; *(us8*)(dw + 8) = wvC[1];
                *(us8*)(dw + 16) = wvC[2]; *(us8*)(dw + 24) = wvC[3];
            }
        }
        __syncthreads();
        if (kk2 < 5) {  // prefetch next step while MFMAing this one
            const int kn = kk2 + 1;
            const unsigned short* src =
                kn == 1 ? s1 : (kn == 2 ? s2 : (kn == 3 ? s3 : (kn == 4 ? s4 : s5)));
            const int stride = (kn & 1) ? strideSt : NN;
            const unsigned short* a = src + (size_t)(n0 + dn) * stride + q * 32;
            avN[0] = *(const us8*)(a);      avN[1] = *(const us8*)(a + 8);
            avN[2] = *(const us8*)(a + 16); avN[3] = *(const us8*)(a + 24);
            if (o < OC) {
                const unsigned short* ww = Wt + o * 384 + kn * 64 + wq * 32;
                wvN[0] = *(const us8*)(ww);      wvN[1] = *(const us8*)(ww + 8);
                wvN[2] = *(const us8*)(ww + 16); wvN[3] = *(const us8*)(ww + 24);
            }
        }
#pragma unroll
        for (int ss = 0; ss < 2; ++ss) {
            const int kb = ss * 32 + (l >> 4) * 8;
            bf16x8 bf0 = *(const bf16x8*)(&W_lds[(colBaseW + (l & 15)) * 72 + kb]);
            bf16x8 bf1 = *(const bf16x8*)(&W_lds[(colBaseW + 16 + (l & 15)) * 72 + kb]);
#pragma unroll
            for (int mf = 0; mf < MF; ++mf) {
                int r = rowBaseW + mf * 16 + (l & 15);
                bf16x8 a = *(const bf16x8*)(&A_lds[r * 72 + kb]);
                acc[mf][0] = __builtin_amdgcn_mfma_f32_16x16x32_bf16(a, bf0, acc[mf][0], 0, 0, 0);
                acc[mf][1] = __builtin_amdgcn_mfma_f32_16x16x32_bf16(a, bf1, acc[mf][1], 0, 0, 0);
            }
        }
        if (kk2 < 5) {
#pragma unroll
            for (int i = 0; i < 4; ++i) { avC[i] = avN[i]; wvC[i] = wvN[i]; }
        }
    }

    // epilogue: fragment D row = rowBase + mf*16 + (l>>4)*4 + rr;  r = dn*32 + b
    const int l4 = (l >> 4) * 4;
    const int lc = l & 15;
    if (GATE) {
#pragma unroll
        for (int mf = 0; mf < MF; ++mf) {
#pragma unroll
            for (int nf = 0; nf < 2; ++nf) {
                int col = colBaseW + nf * 16 + lc;
#pragma unroll
                for (int rr = 0; rr < 4; ++rr) {
                    int r = mf * 16 + l4 + rr;
                    int nn = n0 + (r >> 5);
                    int b = r & 31;
                    float vv = acc[mf][nf][rr] + bias[col];
                    float s = 1.f / (1.f + __expf(-vv));
                    if (col < 64) {  // wave-uniform: waves 0,1 = r-gate, 2,3 = u-gate
                        float h = hx[(size_t)b * (NN * UU) + (size_t)nn * UU + col];
                        x2st[(size_t)nn * 2048 + b * 64 + col] = f2bf(s * h);
                    } else {
                        ubuf[(size_t)b * (NN * UU) + (size_t)nn * UU + (col - 64)] = f2bf(s);
                    }
                }
            }
        }
    } else {
#pragma unroll
        for (int mf = 0; mf < MF; ++mf) {
#pragma unroll
            for (int nf = 0; nf < 2; ++nf) {
                int col = colBaseW + nf * 16 + lc;
#pragma unroll
                for (int rr = 0; rr < 4; ++rr) {
                    int r = rowBaseW + mf * 16 + l4 + rr;
                    int nn = n0 + (r >> 5);
                    int b = r & 31;
                    size_t idx = (size_t)b * (NN * UU) + (size_t)nn * UU + col;
                    float cc = tanhf(acc[mf][nf][rr] + bias[col]);
                    float u = bf2f(ubuf[idx]);
                    float h = hx[idx];
                    outp[idx] = u * h + (1.f - u) * cc;
                }
            }
        }
    }
}

// ---------------------------------------------------------------------------
extern "C" void kernel_launch(void* const* d_in, const int* in_sizes, int n_in,
                              void* d_out, int out_size, void* d_ws, size_t ws_size,
                              hipStream_t stream) {
    const float* inputs  = (const float*)d_in[0];
    const float* hx      = (const float*)d_in[1];
    const float* support = (const float*)d_in[2];
    const float* W_ru    = (const float*)d_in[3];
    const float* b_ru    = (const float*)d_in[4];
    const float* W_c     = (const float*)d_in[5];
    const float* b_c     = (const float*)d_in[6];
    float* out = (float*)d_out;

    char* ws = (char*)d_ws;
    size_t off = 0;
    auto alloc = [&](size_t bytes) -> char* {
        char* p = ws + off;
        off = (off + bytes + 255) & ~(size_t)255;
        return p;
    };
    int*            colsI = (int*)  alloc((size_t)NN * MAXNNZ * 4);
    float*          valsF = (float*)alloc((size_t)NN * MAXNNZ * 4);
    int*            cntI  = (int*)  alloc((size_t)NN * 4);
    unsigned short* Wt1   = (unsigned short*)alloc(128 * 384 * 2);
    unsigned short* Wt2   = (unsigned short*)alloc(64 * 384 * 2);
    unsigned short* Xall  = (unsigned short*)alloc((size_t)NN * 4096 * 2);
    unsigned short* Z1    = (unsigned short*)alloc((size_t)NN * 4096 * 2);
    unsigned short* Z2    = (unsigned short*)alloc((size_t)NN * 4096 * 2);
    unsigned short* X2st  = (unsigned short*)alloc((size_t)NN * 2048 * 2);
    unsigned short* Z1st  = (unsigned short*)alloc((size_t)NN * 2048 * 2);
    unsigned short* Z2st  = (unsigned short*)alloc((size_t)NN * 2048 * 2);
    unsigned short* ubuf  = (unsigned short*)alloc((size_t)BB * NN * UU * 2);
    if (off > ws_size) return;  // workspace too small -> loud validation failure

    build_ell<<<1024, 256, 0, stream>>>(support, colsI, valsF, cntI);
    build_x0<<<16384, 256, 0, stream>>>(inputs, hx, Xall);
    prep_w<<<288, 256, 0, stream>>>(W_ru, W_c, Wt1, Wt2);

    // gconv1 diffusion over all 4096 columns (8 chunks of 512)
    spmm_kernel<false><<<8192, 256, 0, stream>>>(colsI, valsF, cntI, Xall, Xall, Z1, 4096);
    spmm_kernel<true><<<8192, 256, 0, stream>>>(colsI, valsF, cntI, Z1, Xall, Z2, 4096);
    // gate GEMM -> r*h (X2st) and u (ubuf)
    gemm_kernel<true><<<1024, 256, 0, stream>>>(Xall, Xall + 2048, Z1, Z1 + 2048,
                                                Z2, Z2 + 2048, 4096, Wt1, b_ru, hx,
                                                ubuf, X2st, nullptr);
    // gconv2 diffusion: only the 2048 state columns (4 chunks of 512)
    spmm_kernel<false><<<4096, 256, 0, stream>>>(colsI, valsF, cntI, X2st, X2st, Z1st, 2048);
    spmm_kernel<true><<<4096, 256, 0, stream>>>(colsI, valsF, cntI, Z1st, X2st, Z2st, 2048);
    // candidate GEMM + GRU combine -> out
    gemm_kernel<false><<<1024, 256, 0, stream>>>(Xall, X2st, Z1, Z1st, Z2, Z2st, 2048,
                                                 Wt2, b_c, hx, ubuf, nullptr, out);
}